// Round 4
// baseline (884.836 us; speedup 1.0000x reference)
//
#include <hip/hip_runtime.h>

namespace {

constexpr int NN = 50000;   // nodes
constexpr int NE = 800000;  // edges
constexpr int NB = 64;      // graphs / batch
constexpr int NL = 32;      // path length
constexpr int ND = 256;     // D == H == 256
constexpr int NSCAN = 196;  // ceil(50176/256) scan blocks
constexpr int NPOOL = (NN + 63) / 64;  // 782 pool blocks

typedef __attribute__((ext_vector_type(8))) short short8v;  // 8 bf16 (4 VGPRs)
typedef __attribute__((ext_vector_type(4))) float float4v;  // MFMA accumulator

__device__ __forceinline__ float sigf(float x){ return 1.0f/(1.0f + __expf(-x)); }

__device__ __forceinline__ ushort rne_bf16(float f){
  uint u = __float_as_uint(f);
  return (ushort)((u + 0x7FFFu + ((u >> 16) & 1u)) >> 16);
}
__device__ __forceinline__ float bf2f(ushort u){ return __uint_as_float((uint)u << 16); }

// hi = RNE-bf16(f), lo = trunc-bf16(f - hi): hi is the RNE value (usable standalone),
// hi+lo reconstructs f to ~2^-17 rel.
__device__ __forceinline__ void splitr(float f, ushort& h, ushort& lo){
  h = rne_bf16(f);
  float r = f - bf2f(h);
  lo = (ushort)(__float_as_uint(r) >> 16);
}

// split 8 fp32 -> 8 bf16-hi (truncated) + 8 bf16-lo (of remainder), packed 2/word
__device__ __forceinline__ void split8(float4 fa, float4 fb, uint4& h, uint4& lo){
  uint a0=__float_as_uint(fa.x), a1=__float_as_uint(fa.y), a2=__float_as_uint(fa.z), a3=__float_as_uint(fa.w);
  uint b0=__float_as_uint(fb.x), b1=__float_as_uint(fb.y), b2=__float_as_uint(fb.z), b3=__float_as_uint(fb.w);
  h.x = (a0>>16) | (a1 & 0xFFFF0000u);
  h.y = (a2>>16) | (a3 & 0xFFFF0000u);
  h.z = (b0>>16) | (b1 & 0xFFFF0000u);
  h.w = (b2>>16) | (b3 & 0xFFFF0000u);
  float r0 = fa.x - __uint_as_float(a0 & 0xFFFF0000u);
  float r1 = fa.y - __uint_as_float(a1 & 0xFFFF0000u);
  float r2 = fa.z - __uint_as_float(a2 & 0xFFFF0000u);
  float r3 = fa.w - __uint_as_float(a3 & 0xFFFF0000u);
  float r4 = fb.x - __uint_as_float(b0 & 0xFFFF0000u);
  float r5 = fb.y - __uint_as_float(b1 & 0xFFFF0000u);
  float r6 = fb.z - __uint_as_float(b2 & 0xFFFF0000u);
  float r7 = fb.w - __uint_as_float(b3 & 0xFFFF0000u);
  lo.x = (__float_as_uint(r0)>>16) | (__float_as_uint(r1) & 0xFFFF0000u);
  lo.y = (__float_as_uint(r2)>>16) | (__float_as_uint(r3) & 0xFFFF0000u);
  lo.z = (__float_as_uint(r4)>>16) | (__float_as_uint(r5) & 0xFFFF0000u);
  lo.w = (__float_as_uint(r6)>>16) | (__float_as_uint(r7) & 0xFFFF0000u);
}

// ================= CSR build (counting sort of edges by dst) =================
__global__ void k_hist(const int* __restrict__ dst, int* __restrict__ cnt){
  int stride = gridDim.x * blockDim.x;
  for (int e = blockIdx.x*blockDim.x + threadIdx.x; e < NE; e += stride)
    atomicAdd(&cnt[dst[e]], 1);
}

__global__ void k_scan_block(const int* __restrict__ cnt, int* __restrict__ offs,
                             int* __restrict__ bsum){
  __shared__ int s[256];
  const int t = threadIdx.x, i = blockIdx.x*256 + t;
  int v = cnt[i];
  s[t] = v; __syncthreads();
  #pragma unroll
  for (int off = 1; off < 256; off <<= 1){
    int x = (t >= off) ? s[t-off] : 0;
    __syncthreads();
    s[t] += x;
    __syncthreads();
  }
  offs[i] = s[t] - v;
  if (t == 255) bsum[blockIdx.x] = s[255];
}

__global__ void k_scan_top(const int* __restrict__ bsum, int* __restrict__ bsum2){
  __shared__ int s[256];
  const int t = threadIdx.x;
  int v = (t < NSCAN) ? bsum[t] : 0;
  s[t] = v; __syncthreads();
  #pragma unroll
  for (int off = 1; off < 256; off <<= 1){
    int x = (t >= off) ? s[t-off] : 0;
    __syncthreads();
    s[t] += x;
    __syncthreads();
  }
  if (t < NSCAN) bsum2[t] = s[t] - v;
}

__global__ void k_scan_add(int* __restrict__ offs, const int* __restrict__ bsum2,
                           int* __restrict__ cursor){
  const int i = blockIdx.x*256 + threadIdx.x;
  int v = offs[i] + bsum2[blockIdx.x];
  offs[i] = v;
  cursor[i] = v;
}

__global__ void k_fill(const int* __restrict__ src, const int* __restrict__ dst,
                       int* __restrict__ cursor, int* __restrict__ csr){
  int stride = gridDim.x * blockDim.x;
  for (int e = blockIdx.x*blockDim.x + threadIdx.x; e < NE; e += stride){
    int d = dst[e];
    int pos = atomicAdd(&cursor[d], 1);
    csr[pos] = src[e];
  }
}

// ================= fp32 -> bf16 (RNE) bulk convert =================
__global__ void k_tobf16(const float* __restrict__ in, ushort* __restrict__ out){
  const int i = blockIdx.x*blockDim.x + threadIdx.x;   // one per 8 elems
  const float4 a = ((const float4*)in)[i*2];
  const float4 b = ((const float4*)in)[i*2+1];
  ushort o[8] = { rne_bf16(a.x), rne_bf16(a.y), rne_bf16(a.z), rne_bf16(a.w),
                  rne_bf16(b.x), rne_bf16(b.y), rne_bf16(b.z), rne_bf16(b.w) };
  ((uint4*)out)[i] = *(uint4*)o;
}

// ================= mean-aggregate gather over bf16 features =================
// Output written pre-split RNE-hi / residual-lo.
__launch_bounds__(256, 8)
__global__ void k_gather_bf16(const ushort* __restrict__ feat, const int* __restrict__ offs,
                              const int* __restrict__ csr,
                              ushort* __restrict__ outH, ushort* __restrict__ outL){
  __shared__ float4 sp[256];
  const int u = blockIdx.x, t = threadIdx.x;
  const int w = t >> 6, l = t & 63;
  const int beg = offs[u], end = offs[u+1];
  const int lc = l * 4;
  float a0 = 0.f, a1 = 0.f, a2 = 0.f, a3 = 0.f;
  int e = beg + w;
  for (; e + 4 < end; e += 8){
    int s0 = csr[e], s1 = csr[e+4];
    ushort4 v0 = *(const ushort4*)(feat + (long long)s0*ND + lc);
    ushort4 v1 = *(const ushort4*)(feat + (long long)s1*ND + lc);
    a0 += bf2f(v0.x) + bf2f(v1.x);
    a1 += bf2f(v0.y) + bf2f(v1.y);
    a2 += bf2f(v0.z) + bf2f(v1.z);
    a3 += bf2f(v0.w) + bf2f(v1.w);
  }
  if (e < end){
    int s0 = csr[e];
    ushort4 v0 = *(const ushort4*)(feat + (long long)s0*ND + lc);
    a0 += bf2f(v0.x); a1 += bf2f(v0.y); a2 += bf2f(v0.z); a3 += bf2f(v0.w);
  }
  sp[t] = make_float4(a0, a1, a2, a3);
  __syncthreads();
  if (t < 64){
    float4 p0 = sp[t], p1 = sp[64+t], p2 = sp[128+t], p3 = sp[192+t];
    float inv = 1.0f / fmaxf((float)(end - beg), 1.0f);
    float4 r;
    r.x = (p0.x + p1.x + p2.x + p3.x) * inv;
    r.y = (p0.y + p1.y + p2.y + p3.y) * inv;
    r.z = (p0.z + p1.z + p2.z + p3.z) * inv;
    r.w = (p0.w + p1.w + p2.w + p3.w) * inv;
    ushort hh[4], ll[4];
    splitr(r.x, hh[0], ll[0]);
    splitr(r.y, hh[1], ll[1]);
    splitr(r.z, hh[2], ll[2]);
    splitr(r.w, hh[3], ll[3]);
    *(ushort4*)(outH + (long long)u*ND + t*4) = *(ushort4*)hh;
    *(ushort4*)(outL + (long long)u*ND + t*4) = *(ushort4*)ll;
  }
}

// ============ weight prep: fragment-linear swizzled [wl; wr] bf16 hi/lo ============
__global__ void k_wsplit(const float* __restrict__ wl, const float* __restrict__ wr,
                         ushort* __restrict__ WtH, ushort* __restrict__ WtL){
  const int k = blockIdx.x;    // 0..511
  const int n = threadIdx.x;   // 0..255
  float v = (k < 256) ? wl[k*256 + n] : wr[(k-256)*256 + n];
  uint u = __float_as_uint(v);
  float r = v - __uint_as_float(u & 0xFFFF0000u);
  const int wc = n >> 6, nt = (n >> 4) & 3, lm = n & 15;
  const int kk = k >> 5, lq = (k >> 3) & 3, j = k & 7;
  const long long idx = (long long)(((wc*4 + nt)*16 + kk)*64 + lq*16 + lm)*8 + j;
  WtH[idx] = (ushort)(u >> 16);
  WtL[idx] = (ushort)(__float_as_uint(r) >> 16);
}

// ============ layer-1 GEMM: 64x128 blocks, grid (782,2) — ALIAS-FREE ============
// A1 = gather output (pre-split hi/lo). A2 = x read directly from the fp32 INPUT
// tensor (never written) with split8 on the 8 A2 K-steps. Output h1H/h1L disjoint
// from all inputs -> the 2-D grid is race-free. Barrier-free main loop; A-operand
// register dbuf; B loaded per-step (L2-hot, 512 KB). relu hardcoded.
__launch_bounds__(256, 3)
__global__ void k_gemm_l1(const ushort* __restrict__ A1H, const ushort* __restrict__ A1L,
                          const float* __restrict__ A2F,
                          const ushort* __restrict__ WtH, const ushort* __restrict__ WtL,
                          const float* __restrict__ bias,
                          ushort* __restrict__ CH, ushort* __restrict__ CL)
{
  __shared__ float eb[16*132];          // 8.25 KB epilogue staging
  const int t  = threadIdx.x;
  const int w  = t >> 6;                // wave 0..3
  const int l  = t & 63;                // lane
  const int lm = l & 15;
  const int lq = l >> 4;
  const int m0 = blockIdx.x * 64;
  const int n0 = blockIdx.y * 128;

  const uint4* BH4 = (const uint4*)WtH;
  const uint4* BL4 = (const uint4*)WtL;

  const float4v vzero = {0.f, 0.f, 0.f, 0.f};
  float4v acc[4][2];
  #pragma unroll
  for (int i = 0; i < 4; ++i)
    #pragma unroll
    for (int j = 0; j < 2; ++j) acc[i][j] = vzero;

  long long arow[4];
  #pragma unroll
  for (int mt = 0; mt < 4; ++mt){
    int row = m0 + mt*16 + lm;
    row = (row < NN) ? row : (NN - 1);          // clamp into own tile; dup rows unguarded-stored? no: store guard
    arow[mt] = (long long)row * ND;
  }
  int bbase[2];
  #pragma unroll
  for (int j = 0; j < 2; ++j){
    const int ncol = n0 + w*32 + j*16;
    bbase[j] = ((ncol >> 6)*4 + ((ncol >> 4) & 3))*1024 + l;
  }

  auto ldA = [&](int kk, uint4* ah, uint4* al){
    if (kk < 8){
      const int koff = kk*32 + lq*8;
      #pragma unroll
      for (int mt = 0; mt < 4; ++mt){
        ah[mt] = *(const uint4*)(A1H + arow[mt] + koff);
        al[mt] = *(const uint4*)(A1L + arow[mt] + koff);
      }
    } else {
      const int koff = (kk & 7)*32 + lq*8;
      #pragma unroll
      for (int mt = 0; mt < 4; ++mt){
        const float* p = A2F + arow[mt] + koff;
        float4 fa = *(const float4*)p;
        float4 fb = *(const float4*)(p + 4);
        split8(fa, fb, ah[mt], al[mt]);
      }
    }
  };

  uint4 ahb[2][4], alb[2][4];
  ldA(0, ahb[0], alb[0]);

  #pragma unroll
  for (int kk = 0; kk < 16; ++kk){
    const int cur = kk & 1, nx = cur ^ 1;
    // B fragments for this step (L2-hot): issue first
    uint4 bh[2], bl[2];
    #pragma unroll
    for (int j = 0; j < 2; ++j){
      const int idx = bbase[j] + kk*64;
      bh[j] = BH4[idx];
      bl[j] = BL4[idx];
    }
    // prefetch next A tile while MFMAs run on the current one
    if (kk < 15) ldA(kk + 1, ahb[nx], alb[nx]);

    #pragma unroll
    for (int j = 0; j < 2; ++j){
      short8v bhv = *(short8v*)&bh[j];
      short8v blv = *(short8v*)&bl[j];
      #pragma unroll
      for (int mt = 0; mt < 4; ++mt){
        short8v ahv = *(short8v*)&ahb[cur][mt];
        short8v alv = *(short8v*)&alb[cur][mt];
        acc[mt][j] = __builtin_amdgcn_mfma_f32_16x16x32_bf16(ahv, bhv, acc[mt][j], 0, 0, 0);
        acc[mt][j] = __builtin_amdgcn_mfma_f32_16x16x32_bf16(alv, bhv, acc[mt][j], 0, 0, 0);
        acc[mt][j] = __builtin_amdgcn_mfma_f32_16x16x32_bf16(ahv, blv, acc[mt][j], 0, 0, 0);
      }
    }
  }

  // ---- epilogue: LDS transpose per 16-row slab, coalesced RNE-hi/lo stores ----
  float bvv[2];
  #pragma unroll
  for (int j = 0; j < 2; ++j) bvv[j] = bias[n0 + w*32 + j*16 + lm];

  #pragma unroll
  for (int mt = 0; mt < 4; ++mt){
    #pragma unroll
    for (int j = 0; j < 2; ++j){
      #pragma unroll
      for (int r = 0; r < 4; ++r){
        float v = fmaxf(acc[mt][j][r] + bvv[j], 0.f);   // relu (layer 1)
        eb[(lq*4 + r)*132 + w*32 + j*16 + lm] = v;      // C/D: col=lane&15, row=quad*4+reg
      }
    }
    __syncthreads();
    #pragma unroll
    for (int i = 0; i < 2; ++i){
      int idx = i*256 + t;           // 0..511
      int rr  = idx >> 5;            // 0..15
      int c4  = (idx & 31) * 4;      // 0..124
      int grow = m0 + mt*16 + rr;
      if (grow < NN){
        float4 fv = *(float4*)&eb[rr*132 + c4];
        ushort hh[4], ll[4];
        splitr(fv.x, hh[0], ll[0]);
        splitr(fv.y, hh[1], ll[1]);
        splitr(fv.z, hh[2], ll[2]);
        splitr(fv.w, hh[3], ll[3]);
        *(ushort4*)(CH + (long long)grow*ND + n0 + c4) = *(ushort4*)hh;
        *(ushort4*)(CL + (long long)grow*ND + n0 + c4) = *(ushort4*)ll;
      }
    }
    __syncthreads();
  }
}

// ============ layer-2 GEMM: 64x256 blocks, 1-D grid — IN-PLACE SAFE ============
// All operands pre-split hi/lo bf16 (zero split VALU in the loop). One block covers
// the full N and K range of its 64 rows, so in-place output over A2 (h1 -> node_emb)
// is race-free: all loads are consumed before the first epilogue barrier, stores
// follow it, and no other block touches these rows (row clamp stays in-tile).
__launch_bounds__(256, 2)
__global__ void k_gemm_l2(const ushort* A1H, const ushort* A1L,
                          const ushort* A2H, const ushort* A2L,
                          const ushort* __restrict__ WtH, const ushort* __restrict__ WtL,
                          const float* __restrict__ bias,
                          ushort* CH, ushort* CL)
{
  __shared__ float eb[16*260];          // 16.6 KB epilogue staging
  const int t  = threadIdx.x;
  const int w  = t >> 6;                // wave 0..3
  const int l  = t & 63;                // lane
  const int lm = l & 15;
  const int lq = l >> 4;
  const int m0 = blockIdx.x * 64;

  const uint4* BH4 = (const uint4*)WtH;
  const uint4* BL4 = (const uint4*)WtL;

  const float4v vzero = {0.f, 0.f, 0.f, 0.f};
  float4v acc[4][4];
  #pragma unroll
  for (int i = 0; i < 4; ++i)
    #pragma unroll
    for (int j = 0; j < 4; ++j) acc[i][j] = vzero;

  long long arow[4];
  #pragma unroll
  for (int mt = 0; mt < 4; ++mt){
    int row = m0 + mt*16 + lm;
    row = (row < NN) ? row : (NN - 1);
    arow[mt] = (long long)row * ND;
  }
  int bbase[4];
  #pragma unroll
  for (int nt = 0; nt < 4; ++nt) bbase[nt] = (w*4 + nt)*1024 + l;

  auto ldB = [&](int kk, uint4* bh, uint4* bl){
    #pragma unroll
    for (int nt = 0; nt < 4; ++nt){
      const int idx = bbase[nt] + kk*64;
      bh[nt] = BH4[idx];
      bl[nt] = BL4[idx];
    }
  };
  auto ldA = [&](int kk, uint4* ah, uint4* al){
    const ushort* Hb = (kk < 8) ? A1H : A2H;    // constant-folds under full unroll
    const ushort* Lb = (kk < 8) ? A1L : A2L;
    const int koff = (kk & 7)*32 + lq*8;
    #pragma unroll
    for (int mt = 0; mt < 4; ++mt){
      ah[mt] = *(const uint4*)(Hb + arow[mt] + koff);
      al[mt] = *(const uint4*)(Lb + arow[mt] + koff);
    }
  };

  uint4 bhb[2][4], blb[2][4], ahb[2][4], alb[2][4];
  ldB(0, bhb[0], blb[0]);
  ldA(0, ahb[0], alb[0]);

  #pragma unroll
  for (int kk = 0; kk < 16; ++kk){
    const int cur = kk & 1, nx = cur ^ 1;
    if (kk < 15){
      ldB(kk + 1, bhb[nx], blb[nx]);
      ldA(kk + 1, ahb[nx], alb[nx]);
    }
    #pragma unroll
    for (int nt = 0; nt < 4; ++nt){
      short8v bhv = *(short8v*)&bhb[cur][nt];
      short8v blv = *(short8v*)&blb[cur][nt];
      #pragma unroll
      for (int mt = 0; mt < 4; ++mt){
        short8v ahv = *(short8v*)&ahb[cur][mt];
        short8v alv = *(short8v*)&alb[cur][mt];
        acc[mt][nt] = __builtin_amdgcn_mfma_f32_16x16x32_bf16(ahv, bhv, acc[mt][nt], 0, 0, 0);
        acc[mt][nt] = __builtin_amdgcn_mfma_f32_16x16x32_bf16(alv, bhv, acc[mt][nt], 0, 0, 0);
        acc[mt][nt] = __builtin_amdgcn_mfma_f32_16x16x32_bf16(ahv, blv, acc[mt][nt], 0, 0, 0);
      }
    }
  }

  // ---- epilogue: LDS transpose per 16-row slab, coalesced RNE-hi/lo stores ----
  float bvv[4];
  #pragma unroll
  for (int nt = 0; nt < 4; ++nt) bvv[nt] = bias[w*64 + nt*16 + lm];

  #pragma unroll
  for (int mt = 0; mt < 4; ++mt){
    #pragma unroll
    for (int nt = 0; nt < 4; ++nt){
      #pragma unroll
      for (int r = 0; r < 4; ++r){
        float v = acc[mt][nt][r] + bvv[nt];             // no relu (layer 2)
        eb[(lq*4 + r)*260 + w*64 + nt*16 + lm] = v;
      }
    }
    __syncthreads();
    #pragma unroll
    for (int i = 0; i < 4; ++i){
      int idx = i*256 + t;           // 0..1023
      int rr  = idx >> 6;            // 0..15
      int c4  = (idx & 63) * 4;      // 0..252
      int grow = m0 + mt*16 + rr;
      if (grow < NN){
        float4 fv = *(float4*)&eb[rr*260 + c4];
        ushort hh[4], ll[4];
        splitr(fv.x, hh[0], ll[0]);
        splitr(fv.y, hh[1], ll[1]);
        splitr(fv.z, hh[2], ll[2]);
        splitr(fv.w, hh[3], ll[3]);
        *(ushort4*)(CH + (long long)grow*ND + c4) = *(ushort4*)hh;
        *(ushort4*)(CL + (long long)grow*ND + c4) = *(ushort4*)ll;
      }
    }
    __syncthreads();
  }
}

// ---------------- LSTM input gates ----------------
__launch_bounds__(256, 3)
__global__ void k_xgate(const ushort* __restrict__ EH, const ushort* __restrict__ EL,
                        const int* __restrict__ paths,
                        const float* __restrict__ w_ih, const float* __restrict__ b_ih,
                        const float* __restrict__ b_hh, float* __restrict__ xg)
{
  __shared__ float As[16][68];
  __shared__ float Ws[16][260];
  const int t  = threadIdx.x;
  const int m0 = blockIdx.x * 64;    // path rows (2048 total)
  const int g0 = blockIdx.y * 256;   // gate cols (1024 total)
  const int rg = t >> 5, cg = t & 31;
  const int sm = t >> 2, sj = (t & 3) * 4;

  float acc[8][8];
  #pragma unroll
  for (int i = 0; i < 8; ++i)
    #pragma unroll
    for (int j = 0; j < 8; ++j) acc[i][j] = 0.f;

  const int node = paths[m0 + sm];
  const ushort* ehrow = EH + (long long)node*ND;
  const ushort* elrow = EL + (long long)node*ND;
  const float* wrow = w_ih + (long long)(g0 + t)*ND;

  for (int k0 = 0; k0 < 256; k0 += 16){
    ushort4 hv = *(const ushort4*)(ehrow + k0 + sj);
    ushort4 lv = *(const ushort4*)(elrow + k0 + sj);
    float av0 = bf2f(hv.x) + bf2f(lv.x);
    float av1 = bf2f(hv.y) + bf2f(lv.y);
    float av2 = bf2f(hv.z) + bf2f(lv.z);
    float av3 = bf2f(hv.w) + bf2f(lv.w);
    float4 q0 = *(const float4*)(wrow + k0 + 0);
    float4 q1 = *(const float4*)(wrow + k0 + 4);
    float4 q2 = *(const float4*)(wrow + k0 + 8);
    float4 q3 = *(const float4*)(wrow + k0 + 12);
    __syncthreads();
    As[sj+0][sm]=av0; As[sj+1][sm]=av1; As[sj+2][sm]=av2; As[sj+3][sm]=av3;
    Ws[ 0][t]=q0.x; Ws[ 1][t]=q0.y; Ws[ 2][t]=q0.z; Ws[ 3][t]=q0.w;
    Ws[ 4][t]=q1.x; Ws[ 5][t]=q1.y; Ws[ 6][t]=q1.z; Ws[ 7][t]=q1.w;
    Ws[ 8][t]=q2.x; Ws[ 9][t]=q2.y; Ws[10][t]=q2.z; Ws[11][t]=q2.w;
    Ws[12][t]=q3.x; Ws[13][t]=q3.y; Ws[14][t]=q3.z; Ws[15][t]=q3.w;
    __syncthreads();
    #pragma unroll
    for (int k = 0; k < 16; ++k){
      float a[8], b[8];
      *(float4*)&a[0] = *(const float4*)&As[k][rg*8];
      *(float4*)&a[4] = *(const float4*)&As[k][rg*8+4];
      *(float4*)&b[0] = *(const float4*)&Ws[k][cg*8];
      *(float4*)&b[4] = *(const float4*)&Ws[k][cg*8+4];
      #pragma unroll
      for (int i = 0; i < 8; ++i)
        #pragma unroll
        for (int j = 0; j < 8; ++j)
          acc[i][j] = fmaf(a[i], b[j], acc[i][j]);
    }
  }

  float bv[8];
  #pragma unroll
  for (int j = 0; j < 8; ++j){ int g = g0 + cg*8 + j; bv[j] = b_ih[g] + b_hh[g]; }
  #pragma unroll
  for (int i = 0; i < 8; ++i){
    int row = m0 + rg*8 + i;
    float o[8];
    #pragma unroll
    for (int j = 0; j < 8; ++j) o[j] = acc[i][j] + bv[j];
    *(float4*)(xg + (long long)row*1024 + g0 + cg*8 + 0) = *(float4*)&o[0];
    *(float4*)(xg + (long long)row*1024 + g0 + cg*8 + 4) = *(float4*)&o[4];
  }
}

// ---------------- one LSTM step ----------------
__launch_bounds__(256, 4)
__global__ void k_lstm_step(const float* __restrict__ h_in, float* __restrict__ h_out,
                            float* __restrict__ c_state, const float* __restrict__ xg,
                            const float* __restrict__ w_hh, int tstep)
{
  __shared__ float ws[4*256];
  __shared__ float hs[32*260];
  __shared__ float part[2*128];
  __shared__ float gs[128];
  const int t  = threadIdx.x;
  const int u  = blockIdx.x >> 1;
  const int b0 = (blockIdx.x & 1) * 32;

  {
    int gate = t >> 6, c4 = (t & 63) * 4;
    float4 v = *(const float4*)(w_hh + (long long)(gate*256 + u)*256 + c4);
    *(float4*)&ws[gate*256 + c4] = v;
  }
  #pragma unroll
  for (int i = 0; i < 8; ++i){
    int idx = i*256 + t;
    int b = idx >> 6, c4 = (idx & 63) * 4;
    float4 v = *(const float4*)(h_in + (long long)(b0 + b)*256 + c4);
    *(float4*)&hs[b*260 + c4] = v;
  }
  __syncthreads();

  const int b  = t & 31;
  const int g  = (t >> 5) & 3;
  const int kd = t >> 7;
  float s = 0.f;
  const float* hp = &hs[b*260 + kd*128];
  const float* wp = &ws[g*256 + kd*128];
  #pragma unroll
  for (int k4 = 0; k4 < 32; ++k4){
    float4 h4 = *(const float4*)(hp + k4*4);
    float4 w4 = *(const float4*)(wp + k4*4);
    s += h4.x*w4.x + h4.y*w4.y + h4.z*w4.z + h4.w*w4.w;
  }
  part[kd*128 + b*4 + g] = s;
  __syncthreads();

  if (t < 128){
    int bb = t >> 2, gg = t & 3;
    const float* xp = xg + ((long long)(b0 + bb)*NL + tstep)*1024;
    gs[t] = part[t] + part[128 + t] + xp[gg*256 + u];
  }
  __syncthreads();

  if (t < 32){
    float gi = gs[t*4+0], gf = gs[t*4+1], gG = gs[t*4+2], go = gs[t*4+3];
    int bb = b0 + t;
    float c_old = c_state[bb*256 + u];
    float c_new = sigf(gf)*c_old + sigf(gi)*tanhf(gG);
    c_state[bb*256 + u] = c_new;
    h_out[bb*256 + u] = sigf(go)*tanhf(c_new);
  }
}

// ---------------- global mean pool (hi/lo bf16 input), chunk-parallel ----------------
__launch_bounds__(256, 8)
__global__ void k_pool(const ushort* __restrict__ EH, const ushort* __restrict__ EL,
                       const int* __restrict__ batch,
                       float* __restrict__ gsum, float* __restrict__ gcnt)
{
  __shared__ int bs[64];
  __shared__ int uni;
  __shared__ float spf[8*256];
  const int t  = threadIdx.x;
  const int m0 = blockIdx.x * 64;
  const int r  = t >> 5;        // row-lane 0..7
  const int c  = t & 31;        // colgroup 0..31 (8 elems each)
  if (t == 0) uni = 1;
  if (t < 64){
    int n = m0 + t;
    bs[t] = (n < NN) ? batch[n] : -1;
  }
  __syncthreads();
  if (t < 64 && bs[t] != bs[0]) uni = 0;
  __syncthreads();

  const ushort* eh = EH + (long long)m0*ND + c*8;
  const ushort* el = EL + (long long)m0*ND + c*8;

  if (uni){
    float a[8];
    #pragma unroll
    for (int j = 0; j < 8; ++j) a[j] = 0.f;
    #pragma unroll
    for (int i = 0; i < 8; ++i){
      const int row = r*8 + i;
      const uint4 hv = *(const uint4*)(eh + (long long)row*ND);
      const uint4 lv = *(const uint4*)(el + (long long)row*ND);
      const ushort* hp = (const ushort*)&hv;
      const ushort* lp = (const ushort*)&lv;
      #pragma unroll
      for (int j = 0; j < 8; ++j) a[j] += bf2f(hp[j]) + bf2f(lp[j]);
    }
    #pragma unroll
    for (int j = 0; j < 8; ++j) spf[r*256 + c*8 + j] = a[j];
    __syncthreads();
    float s = spf[t] + spf[256+t] + spf[512+t] + spf[768+t]
            + spf[1024+t] + spf[1280+t] + spf[1536+t] + spf[1792+t];
    const int g = bs[0];
    unsafeAtomicAdd(&gsum[g*256 + t], s);
    if (t == 0) unsafeAtomicAdd(&gcnt[g], 64.0f);
  } else {
    float a[8];
    #pragma unroll
    for (int j = 0; j < 8; ++j) a[j] = 0.f;
    int cur = -1, cnt = 0;
    #pragma unroll
    for (int i = 0; i < 8; ++i){
      const int row = r*8 + i;
      const int g = bs[row];
      if (g != cur){
        if (cur >= 0){
          #pragma unroll
          for (int j = 0; j < 8; ++j) unsafeAtomicAdd(&gsum[cur*256 + c*8 + j], a[j]);
          if (c == 0) unsafeAtomicAdd(&gcnt[cur], (float)cnt);
        }
        #pragma unroll
        for (int j = 0; j < 8; ++j) a[j] = 0.f;
        cnt = 0; cur = g;
      }
      if (g >= 0){
        const uint4 hv = *(const uint4*)(eh + (long long)row*ND);
        const uint4 lv = *(const uint4*)(el + (long long)row*ND);
        const ushort* hp = (const ushort*)&hv;
        const ushort* lp = (const ushort*)&lv;
        #pragma unroll
        for (int j = 0; j < 8; ++j) a[j] += bf2f(hp[j]) + bf2f(lp[j]);
        ++cnt;
      }
    }
    if (cur >= 0){
      #pragma unroll
      for (int j = 0; j < 8; ++j) unsafeAtomicAdd(&gsum[cur*256 + c*8 + j], a[j]);
      if (c == 0) unsafeAtomicAdd(&gcnt[cur], (float)cnt);
    }
  }
}

// ---------------- scorer MLP (pool-finalize + concat fused in) ----------------
__global__ void k_score(const float* __restrict__ gsum, const float* __restrict__ gcnt,
                        const float* __restrict__ hfin, const float* __restrict__ wm1,
                        const float* __restrict__ bm1, const float* __restrict__ wm2,
                        const float* __restrict__ bm2, float* __restrict__ out)
{
  __shared__ float cs[512];
  __shared__ float red[4];
  const int b = blockIdx.x, t = threadIdx.x;
  float inv = 1.0f / fmaxf(gcnt[b], 1.0f);
  cs[t]       = gsum[b*256 + t] * inv;
  cs[256 + t] = hfin[b*256 + t];
  __syncthreads();
  float v = 0.f;
  #pragma unroll 4
  for (int k = 0; k < 512; ++k) v = fmaf(cs[k], wm1[(long long)k*256 + t], v);
  v = fmaxf(v + bm1[t], 0.f) * wm2[t];
  #pragma unroll
  for (int off = 32; off > 0; off >>= 1) v += __shfl_down(v, off, 64);
  if ((t & 63) == 0) red[t >> 6] = v;
  __syncthreads();
  if (t == 0) out[b] = red[0] + red[1] + red[2] + red[3] + bm2[0];
}

} // namespace

extern "C" void kernel_launch(void* const* d_in, const int* in_sizes, int n_in,
                              void* d_out, int out_size, void* d_ws, size_t ws_size,
                              hipStream_t stream)
{
  const float* x     = (const float*)d_in[0];
  const int*   eidx  = (const int*)  d_in[1];
  const int*   batch = (const int*)  d_in[2];
  const int*   paths = (const int*)  d_in[3];
  const float* w1l   = (const float*)d_in[4];
  const float* b1l   = (const float*)d_in[5];
  const float* w1r   = (const float*)d_in[6];
  const float* w2l   = (const float*)d_in[7];
  const float* b2l   = (const float*)d_in[8];
  const float* w2r   = (const float*)d_in[9];
  const float* w_ih  = (const float*)d_in[10];
  const float* w_hh  = (const float*)d_in[11];
  const float* b_ih  = (const float*)d_in[12];
  const float* b_hh  = (const float*)d_in[13];
  const float* wm1   = (const float*)d_in[14];
  const float* bm1   = (const float*)d_in[15];
  const float* wm2   = (const float*)d_in[16];
  const float* bm2   = (const float*)d_in[17];

  const int* src = eidx;        // edge_index[0]
  const int* dst = eidx + NE;   // edge_index[1]

  // workspace layout (same footprint as the original session, ~138 MB)
  float* w    = (float*)d_ws;
  float* bufA = w;                         // region0: gather out hi/lo (2 x NN*ND ushort)
  float* bufB = bufA + (long long)NN*ND;   // region1: h1 hi/lo -> node_emb hi/lo (in-place)
  float* xg   = bufB + (long long)NN*ND;   // 2048*1024 floats
  float* gsum = xg   + 2048*1024;          // 64*256
  float* gcnt = gsum + NB*ND;              // 64
  float* h0   = gcnt + 64;                 // 64*256
  float* c0   = h0   + NB*ND;              // 64*256
  float* h1   = c0   + NB*ND;              // 64*256
  ushort* wt1H = (ushort*)(h1 + NB*ND);    // 256*512 each (bf16, fragment-swizzled)
  ushort* wt1L = wt1H + 256*512;
  ushort* wt2H = wt1L + 256*512;
  ushort* wt2L = wt2H + 256*512;
  ushort* fb16 = wt2L + 256*512;           // N*256 bf16: x RNE copy (gather-1 input)

  ushort* A1H = (ushort*)bufA;             // gather mean, hi
  ushort* A1L = A1H + (long long)NN*ND;    // gather mean, lo
  ushort* h1H = (ushort*)bufB;             // h1 RNE-hi (layer1 out) -> node_emb hi (layer2, in-place)
  ushort* h1L = h1H + (long long)NN*ND;    // h1 residual-lo       -> node_emb lo

  // CSR scratch aliased into xg region (dead until k_xgate runs, after layer 2)
  int* cnt    = (int*)xg;        // 50432
  int* offs   = cnt    + 50432;  // 50432
  int* cursor = offs   + 50432;  // 50432
  int* bsum   = cursor + 50432;  // 256
  int* bsum2  = bsum   + 256;    // 256
  int* csr    = bsum2  + 256;    // 800000

  // ---- weight prep (fragment-swizzled bf16 hi/lo split) ----
  k_wsplit<<<512, 256, 0, stream>>>(w1l, w1r, wt1H, wt1L);
  k_wsplit<<<512, 256, 0, stream>>>(w2l, w2r, wt2H, wt2L);

  // ---- x -> bf16 RNE copy (gather-1 input) ----
  k_tobf16<<<(NN*ND/8 + 255)/256, 256, 0, stream>>>(x, fb16);

  // ---- build CSR (counting sort by dst), shared by both layers ----
  hipMemsetAsync(cnt, 0, 50432*sizeof(int), stream);
  k_hist<<<1024, 256, 0, stream>>>(dst, cnt);
  k_scan_block<<<NSCAN, 256, 0, stream>>>(cnt, offs, bsum);
  k_scan_top<<<1, 256, 0, stream>>>(bsum, bsum2);
  k_scan_add<<<NSCAN, 256, 0, stream>>>(offs, bsum2, cursor);
  k_fill<<<1024, 256, 0, stream>>>(src, dst, cursor, csr);

  // ---- layer 1: gather-mean (pre-split), 2-D-grid GEMM (A2 = x fp32, alias-free) ----
  k_gather_bf16<<<NN, 256, 0, stream>>>(fb16, offs, csr, A1H, A1L);
  k_gemm_l1<<<dim3(782, 2), 256, 0, stream>>>(A1H, A1L, x, wt1H, wt1L, b1l, h1H, h1L);

  // ---- layer 2: gather over RNE(relu(h1)) = h1H; 1-D GEMM writes node_emb in-place ----
  k_gather_bf16<<<NN, 256, 0, stream>>>(h1H, offs, csr, A1H, A1L);
  k_gemm_l2<<<782, 256, 0, stream>>>(A1H, A1L, h1H, h1L, wt2H, wt2L, b2l, h1H, h1L);

  // ---- global mean pool (chunk-parallel, vectorized) ----
  hipMemsetAsync(gsum, 0, (NB*ND + 64)*sizeof(float), stream);
  k_pool<<<NPOOL, 256, 0, stream>>>(h1H, h1L, batch, gsum, gcnt);

  // ---- LSTM input gates (overwrites the CSR alias region — CSR dead by now) ----
  k_xgate<<<dim3((NB*NL)/64, 1024/256), 256, 0, stream>>>(h1H, h1L, paths, w_ih, b_ih, b_hh, xg);

  // ---- LSTM recurrence: 32 launches, ping-pong h buffers ----
  hipMemsetAsync(h0, 0, 2*(size_t)NB*ND*sizeof(float), stream);  // h0 + c0
  for (int ts = 0; ts < NL; ++ts){
    float* hin  = (ts & 1) ? h1 : h0;
    float* hout = (ts & 1) ? h0 : h1;
    k_lstm_step<<<512, 256, 0, stream>>>(hin, hout, c0, xg, w_hh, ts);
  }
  // ts=31 wrote h0 -> final hidden state

  // ---- fused concat + scorer ----
  k_score<<<NB, 256, 0, stream>>>(gsum, gcnt, h0, wm1, bm1, wm2, bm2, (float*)d_out);
}

// Round 5
// 816.618 us; speedup vs baseline: 1.0835x; 1.0835x over previous
//
#include <hip/hip_runtime.h>

namespace {

constexpr int NN = 50000;   // nodes
constexpr int NE = 800000;  // edges
constexpr int NB = 64;      // graphs / batch
constexpr int NL = 32;      // path length
constexpr int ND = 256;     // D == H == 256
constexpr int NSCAN = 196;  // ceil(50176/256) scan blocks
constexpr int NPOOL = (NN + 63) / 64;  // 782 pool blocks

typedef __attribute__((ext_vector_type(8))) short short8v;  // 8 bf16 (4 VGPRs)
typedef __attribute__((ext_vector_type(4))) float float4v;  // MFMA accumulator

__device__ __forceinline__ float sigf(float x){ return 1.0f/(1.0f + __expf(-x)); }

__device__ __forceinline__ ushort rne_bf16(float f){
  uint u = __float_as_uint(f);
  return (ushort)((u + 0x7FFFu + ((u >> 16) & 1u)) >> 16);
}
__device__ __forceinline__ float bf2f(ushort u){ return __uint_as_float((uint)u << 16); }

// hi = RNE-bf16(f), lo = trunc-bf16(f - hi)
__device__ __forceinline__ void splitr(float f, ushort& h, ushort& lo){
  h = rne_bf16(f);
  float r = f - bf2f(h);
  lo = (ushort)(__float_as_uint(r) >> 16);
}

// split 8 fp32 -> 8 bf16-hi (truncated) + 8 bf16-lo (of remainder), packed 2/word
__device__ __forceinline__ void split8(float4 fa, float4 fb, uint4& h, uint4& lo){
  uint a0=__float_as_uint(fa.x), a1=__float_as_uint(fa.y), a2=__float_as_uint(fa.z), a3=__float_as_uint(fa.w);
  uint b0=__float_as_uint(fb.x), b1=__float_as_uint(fb.y), b2=__float_as_uint(fb.z), b3=__float_as_uint(fb.w);
  h.x = (a0>>16) | (a1 & 0xFFFF0000u);
  h.y = (a2>>16) | (a3 & 0xFFFF0000u);
  h.z = (b0>>16) | (b1 & 0xFFFF0000u);
  h.w = (b2>>16) | (b3 & 0xFFFF0000u);
  float r0 = fa.x - __uint_as_float(a0 & 0xFFFF0000u);
  float r1 = fa.y - __uint_as_float(a1 & 0xFFFF0000u);
  float r2 = fa.z - __uint_as_float(a2 & 0xFFFF0000u);
  float r3 = fa.w - __uint_as_float(a3 & 0xFFFF0000u);
  float r4 = fb.x - __uint_as_float(b0 & 0xFFFF0000u);
  float r5 = fb.y - __uint_as_float(b1 & 0xFFFF0000u);
  float r6 = fb.z - __uint_as_float(b2 & 0xFFFF0000u);
  float r7 = fb.w - __uint_as_float(b3 & 0xFFFF0000u);
  lo.x = (__float_as_uint(r0)>>16) | (__float_as_uint(r1) & 0xFFFF0000u);
  lo.y = (__float_as_uint(r2)>>16) | (__float_as_uint(r3) & 0xFFFF0000u);
  lo.z = (__float_as_uint(r4)>>16) | (__float_as_uint(r5) & 0xFFFF0000u);
  lo.w = (__float_as_uint(r6)>>16) | (__float_as_uint(r7) & 0xFFFF0000u);
}

// ================= CSR build (counting sort of edges by dst) =================
__global__ void k_hist(const int* __restrict__ dst, int* __restrict__ cnt){
  int stride = gridDim.x * blockDim.x;
  for (int e = blockIdx.x*blockDim.x + threadIdx.x; e < NE; e += stride)
    atomicAdd(&cnt[dst[e]], 1);
}

__global__ void k_scan_block(const int* __restrict__ cnt, int* __restrict__ offs,
                             int* __restrict__ bsum){
  __shared__ int s[256];
  const int t = threadIdx.x, i = blockIdx.x*256 + t;
  int v = cnt[i];
  s[t] = v; __syncthreads();
  #pragma unroll
  for (int off = 1; off < 256; off <<= 1){
    int x = (t >= off) ? s[t-off] : 0;
    __syncthreads();
    s[t] += x;
    __syncthreads();
  }
  offs[i] = s[t] - v;
  if (t == 255) bsum[blockIdx.x] = s[255];
}

__global__ void k_scan_top(const int* __restrict__ bsum, int* __restrict__ bsum2){
  __shared__ int s[256];
  const int t = threadIdx.x;
  int v = (t < NSCAN) ? bsum[t] : 0;
  s[t] = v; __syncthreads();
  #pragma unroll
  for (int off = 1; off < 256; off <<= 1){
    int x = (t >= off) ? s[t-off] : 0;
    __syncthreads();
    s[t] += x;
    __syncthreads();
  }
  if (t < NSCAN) bsum2[t] = s[t] - v;
}

__global__ void k_scan_add(int* __restrict__ offs, const int* __restrict__ bsum2,
                           int* __restrict__ cursor){
  const int i = blockIdx.x*256 + threadIdx.x;
  int v = offs[i] + bsum2[blockIdx.x];
  offs[i] = v;
  cursor[i] = v;
}

__global__ void k_fill(const int* __restrict__ src, const int* __restrict__ dst,
                       int* __restrict__ cursor, int* __restrict__ csr){
  int stride = gridDim.x * blockDim.x;
  for (int e = blockIdx.x*blockDim.x + threadIdx.x; e < NE; e += stride){
    int d = dst[e];
    int pos = atomicAdd(&cursor[d], 1);
    csr[pos] = src[e];
  }
}

// ================= fp32 -> bf16 (RNE) bulk convert =================
__global__ void k_tobf16(const float* __restrict__ in, ushort* __restrict__ out){
  const int i = blockIdx.x*blockDim.x + threadIdx.x;   // one per 8 elems
  const float4 a = ((const float4*)in)[i*2];
  const float4 b = ((const float4*)in)[i*2+1];
  ushort o[8] = { rne_bf16(a.x), rne_bf16(a.y), rne_bf16(a.z), rne_bf16(a.w),
                  rne_bf16(b.x), rne_bf16(b.y), rne_bf16(b.z), rne_bf16(b.w) };
  ((uint4*)out)[i] = *(uint4*)o;
}

// ================= mean-aggregate gather over bf16 features =================
// Output written pre-split RNE-hi / residual-lo.
__launch_bounds__(256, 8)
__global__ void k_gather_bf16(const ushort* __restrict__ feat, const int* __restrict__ offs,
                              const int* __restrict__ csr,
                              ushort* __restrict__ outH, ushort* __restrict__ outL){
  __shared__ float4 sp[256];
  const int u = blockIdx.x, t = threadIdx.x;
  const int w = t >> 6, l = t & 63;
  const int beg = offs[u], end = offs[u+1];
  const int lc = l * 4;
  float a0 = 0.f, a1 = 0.f, a2 = 0.f, a3 = 0.f;
  int e = beg + w;
  for (; e + 4 < end; e += 8){
    int s0 = csr[e], s1 = csr[e+4];
    ushort4 v0 = *(const ushort4*)(feat + (long long)s0*ND + lc);
    ushort4 v1 = *(const ushort4*)(feat + (long long)s1*ND + lc);
    a0 += bf2f(v0.x) + bf2f(v1.x);
    a1 += bf2f(v0.y) + bf2f(v1.y);
    a2 += bf2f(v0.z) + bf2f(v1.z);
    a3 += bf2f(v0.w) + bf2f(v1.w);
  }
  if (e < end){
    int s0 = csr[e];
    ushort4 v0 = *(const ushort4*)(feat + (long long)s0*ND + lc);
    a0 += bf2f(v0.x); a1 += bf2f(v0.y); a2 += bf2f(v0.z); a3 += bf2f(v0.w);
  }
  sp[t] = make_float4(a0, a1, a2, a3);
  __syncthreads();
  if (t < 64){
    float4 p0 = sp[t], p1 = sp[64+t], p2 = sp[128+t], p3 = sp[192+t];
    float inv = 1.0f / fmaxf((float)(end - beg), 1.0f);
    float4 r;
    r.x = (p0.x + p1.x + p2.x + p3.x) * inv;
    r.y = (p0.y + p1.y + p2.y + p3.y) * inv;
    r.z = (p0.z + p1.z + p2.z + p3.z) * inv;
    r.w = (p0.w + p1.w + p2.w + p3.w) * inv;
    ushort hh[4], ll[4];
    splitr(r.x, hh[0], ll[0]);
    splitr(r.y, hh[1], ll[1]);
    splitr(r.z, hh[2], ll[2]);
    splitr(r.w, hh[3], ll[3]);
    *(ushort4*)(outH + (long long)u*ND + t*4) = *(ushort4*)hh;
    *(ushort4*)(outL + (long long)u*ND + t*4) = *(ushort4*)ll;
  }
}

// ============ weight prep: fragment-linear swizzled [wl; wr] bf16 hi/lo ============
__global__ void k_wsplit(const float* __restrict__ wl, const float* __restrict__ wr,
                         ushort* __restrict__ WtH, ushort* __restrict__ WtL){
  const int k = blockIdx.x;    // 0..511
  const int n = threadIdx.x;   // 0..255
  float v = (k < 256) ? wl[k*256 + n] : wr[(k-256)*256 + n];
  uint u = __float_as_uint(v);
  float r = v - __uint_as_float(u & 0xFFFF0000u);
  const int wc = n >> 6, nt = (n >> 4) & 3, lm = n & 15;
  const int kk = k >> 5, lq = (k >> 3) & 3, j = k & 7;
  const long long idx = (long long)(((wc*4 + nt)*16 + kk)*64 + lq*16 + lm)*8 + j;
  WtH[idx] = (ushort)(u >> 16);
  WtL[idx] = (ushort)(__float_as_uint(r) >> 16);
}

// ============ unified MFMA SAGE GEMM: 64x256 tile, 1-D grid, pinned deep prefetch ============
// Round-0 skeleton (best measured) + three fixes:
//  (1) A2F32=1: A2 = x fp32 (read-only input, alias-free), split8 at CONSUME time;
//      A2F32=0: all operands pre-split hi/lo (zero split VALU).
//  (2) A prefetch depth 2 (triple-buffered regs), B depth 1 (L2-hot weights).
//  (3) sched_barrier(0) between each step's load-issue cluster and its MFMA cluster:
//      stops the compiler sinking prefetch loads to just-before-use (round-0 VGPR=92
//      proved it collapsed the pipeline; that is the 15% MfmaUtil cause).
// In-place safe (1-D grid, block covers full N,K of its 64 rows; loads drain before
// the first epilogue barrier, stores follow it). A/C pointers NOT __restrict__.
template<int A2F32, int RELU>
__launch_bounds__(256, 2)
__global__ void k_gemm(const ushort* A1H, const ushort* A1L,
                       const ushort* A2H, const ushort* A2L,
                       const float*  A2F,
                       const ushort* __restrict__ WtH, const ushort* __restrict__ WtL,
                       const float* __restrict__ bias,
                       ushort* CH, ushort* CL)
{
  __shared__ float eb[16*260];          // 16.6 KB epilogue staging
  const int t  = threadIdx.x;
  const int w  = t >> 6;                // wave 0..3
  const int l  = t & 63;                // lane
  const int lm = l & 15;
  const int lq = l >> 4;
  const int m0 = blockIdx.x * 64;

  const uint4* BH4 = (const uint4*)WtH;
  const uint4* BL4 = (const uint4*)WtL;

  const float4v vzero = {0.f, 0.f, 0.f, 0.f};
  float4v acc[4][4];
  #pragma unroll
  for (int i = 0; i < 4; ++i)
    #pragma unroll
    for (int j = 0; j < 4; ++j) acc[i][j] = vzero;

  long long arow[4];
  #pragma unroll
  for (int mt = 0; mt < 4; ++mt){
    int row = m0 + mt*16 + lm;
    row = (row < NN) ? row : (NN - 1);  // clamp in-tile; dup rows discarded by store guard
    arow[mt] = (long long)row * ND;
  }
  int bbase[4];
  #pragma unroll
  for (int nt = 0; nt < 4; ++nt) bbase[nt] = (w*4 + nt)*1024 + l;

  // A pipeline (depth 2): aP/aQ hold hi/lo uint4 (pre-split) or fa/fb bits (fp32 path)
  uint4 aP[3][4], aQ[3][4];
  // B pipeline (depth 1)
  uint4 bh[2][4], bl[2][4];

  auto ldB = [&](int kk, int s){
    #pragma unroll
    for (int nt = 0; nt < 4; ++nt){
      const int idx = bbase[nt] + kk*64;
      bh[s][nt] = BH4[idx];
      bl[s][nt] = BL4[idx];
    }
  };
  auto ldA = [&](int kk, int s){
    const int koff = (kk & 7)*32 + lq*8;
    if (kk < 8 || !A2F32){
      const ushort* Hb = (kk < 8) ? A1H : A2H;
      const ushort* Lb = (kk < 8) ? A1L : A2L;
      #pragma unroll
      for (int mt = 0; mt < 4; ++mt){
        aP[s][mt] = *(const uint4*)(Hb + arow[mt] + koff);
        aQ[s][mt] = *(const uint4*)(Lb + arow[mt] + koff);
      }
    } else {
      #pragma unroll
      for (int mt = 0; mt < 4; ++mt){
        const float* p = A2F + arow[mt] + koff;
        aP[s][mt] = *(const uint4*)p;        // fa bits
        aQ[s][mt] = *(const uint4*)(p + 4);  // fb bits
      }
    }
  };

  ldA(0, 0);
  ldB(0, 0);
  ldA(1, 1);

  #pragma unroll
  for (int kk = 0; kk < 16; ++kk){
    const int c3 = kk % 3;
    const int cB = kk & 1;
    // issue next-step B and step+2 A before computing this step
    if (kk < 15) ldB(kk + 1, cB ^ 1);
    if (kk < 14) ldA(kk + 2, (kk + 2) % 3);
    __builtin_amdgcn_sched_barrier(0);   // pin: loads above may not sink past here

    uint4 ah[4], al[4];
    if (kk < 8 || !A2F32){
      #pragma unroll
      for (int mt = 0; mt < 4; ++mt){ ah[mt] = aP[c3][mt]; al[mt] = aQ[c3][mt]; }
    } else {
      #pragma unroll
      for (int mt = 0; mt < 4; ++mt){
        float4 fa = *(float4*)&aP[c3][mt];
        float4 fb = *(float4*)&aQ[c3][mt];
        split8(fa, fb, ah[mt], al[mt]);
      }
    }

    #pragma unroll
    for (int nt = 0; nt < 4; ++nt){
      short8v bhv = *(short8v*)&bh[cB][nt];
      short8v blv = *(short8v*)&bl[cB][nt];
      #pragma unroll
      for (int mt = 0; mt < 4; ++mt){
        short8v ahv = *(short8v*)&ah[mt];
        short8v alv = *(short8v*)&al[mt];
        acc[mt][nt] = __builtin_amdgcn_mfma_f32_16x16x32_bf16(ahv, bhv, acc[mt][nt], 0, 0, 0);
        acc[mt][nt] = __builtin_amdgcn_mfma_f32_16x16x32_bf16(alv, bhv, acc[mt][nt], 0, 0, 0);
        acc[mt][nt] = __builtin_amdgcn_mfma_f32_16x16x32_bf16(ahv, blv, acc[mt][nt], 0, 0, 0);
      }
    }
  }

  // ---- epilogue: LDS transpose per 16-row slab, coalesced RNE-hi/lo stores ----
  float bvv[4];
  #pragma unroll
  for (int nt = 0; nt < 4; ++nt) bvv[nt] = bias[w*64 + nt*16 + lm];

  #pragma unroll
  for (int mt = 0; mt < 4; ++mt){
    #pragma unroll
    for (int nt = 0; nt < 4; ++nt){
      #pragma unroll
      for (int r = 0; r < 4; ++r){
        float v = acc[mt][nt][r] + bvv[nt];
        if (RELU) v = fmaxf(v, 0.f);
        eb[(lq*4 + r)*260 + w*64 + nt*16 + lm] = v;   // C/D: col=lane&15, row=quad*4+reg
      }
    }
    __syncthreads();
    #pragma unroll
    for (int i = 0; i < 4; ++i){
      int idx = i*256 + t;           // 0..1023
      int rr  = idx >> 6;            // 0..15
      int c4  = (idx & 63) * 4;      // 0..252
      int grow = m0 + mt*16 + rr;
      if (grow < NN){
        float4 fv = *(float4*)&eb[rr*260 + c4];
        ushort hh[4], ll[4];
        splitr(fv.x, hh[0], ll[0]);
        splitr(fv.y, hh[1], ll[1]);
        splitr(fv.z, hh[2], ll[2]);
        splitr(fv.w, hh[3], ll[3]);
        *(ushort4*)(CH + (long long)grow*ND + c4) = *(ushort4*)hh;
        *(ushort4*)(CL + (long long)grow*ND + c4) = *(ushort4*)ll;
      }
    }
    __syncthreads();
  }
}

// ---------------- LSTM input gates ----------------
__launch_bounds__(256, 3)
__global__ void k_xgate(const ushort* __restrict__ EH, const ushort* __restrict__ EL,
                        const int* __restrict__ paths,
                        const float* __restrict__ w_ih, const float* __restrict__ b_ih,
                        const float* __restrict__ b_hh, float* __restrict__ xg)
{
  __shared__ float As[16][68];
  __shared__ float Ws[16][260];
  const int t  = threadIdx.x;
  const int m0 = blockIdx.x * 64;    // path rows (2048 total)
  const int g0 = blockIdx.y * 256;   // gate cols (1024 total)
  const int rg = t >> 5, cg = t & 31;
  const int sm = t >> 2, sj = (t & 3) * 4;

  float acc[8][8];
  #pragma unroll
  for (int i = 0; i < 8; ++i)
    #pragma unroll
    for (int j = 0; j < 8; ++j) acc[i][j] = 0.f;

  const int node = paths[m0 + sm];
  const ushort* ehrow = EH + (long long)node*ND;
  const ushort* elrow = EL + (long long)node*ND;
  const float* wrow = w_ih + (long long)(g0 + t)*ND;

  for (int k0 = 0; k0 < 256; k0 += 16){
    ushort4 hv = *(const ushort4*)(ehrow + k0 + sj);
    ushort4 lv = *(const ushort4*)(elrow + k0 + sj);
    float av0 = bf2f(hv.x) + bf2f(lv.x);
    float av1 = bf2f(hv.y) + bf2f(lv.y);
    float av2 = bf2f(hv.z) + bf2f(lv.z);
    float av3 = bf2f(hv.w) + bf2f(lv.w);
    float4 q0 = *(const float4*)(wrow + k0 + 0);
    float4 q1 = *(const float4*)(wrow + k0 + 4);
    float4 q2 = *(const float4*)(wrow + k0 + 8);
    float4 q3 = *(const float4*)(wrow + k0 + 12);
    __syncthreads();
    As[sj+0][sm]=av0; As[sj+1][sm]=av1; As[sj+2][sm]=av2; As[sj+3][sm]=av3;
    Ws[ 0][t]=q0.x; Ws[ 1][t]=q0.y; Ws[ 2][t]=q0.z; Ws[ 3][t]=q0.w;
    Ws[ 4][t]=q1.x; Ws[ 5][t]=q1.y; Ws[ 6][t]=q1.z; Ws[ 7][t]=q1.w;
    Ws[ 8][t]=q2.x; Ws[ 9][t]=q2.y; Ws[10][t]=q2.z; Ws[11][t]=q2.w;
    Ws[12][t]=q3.x; Ws[13][t]=q3.y; Ws[14][t]=q3.z; Ws[15][t]=q3.w;
    __syncthreads();
    #pragma unroll
    for (int k = 0; k < 16; ++k){
      float a[8], b[8];
      *(float4*)&a[0] = *(const float4*)&As[k][rg*8];
      *(float4*)&a[4] = *(const float4*)&As[k][rg*8+4];
      *(float4*)&b[0] = *(const float4*)&Ws[k][cg*8];
      *(float4*)&b[4] = *(const float4*)&Ws[k][cg*8+4];
      #pragma unroll
      for (int i = 0; i < 8; ++i)
        #pragma unroll
        for (int j = 0; j < 8; ++j)
          acc[i][j] = fmaf(a[i], b[j], acc[i][j]);
    }
  }

  float bv[8];
  #pragma unroll
  for (int j = 0; j < 8; ++j){ int g = g0 + cg*8 + j; bv[j] = b_ih[g] + b_hh[g]; }
  #pragma unroll
  for (int i = 0; i < 8; ++i){
    int row = m0 + rg*8 + i;
    float o[8];
    #pragma unroll
    for (int j = 0; j < 8; ++j) o[j] = acc[i][j] + bv[j];
    *(float4*)(xg + (long long)row*1024 + g0 + cg*8 + 0) = *(float4*)&o[0];
    *(float4*)(xg + (long long)row*1024 + g0 + cg*8 + 4) = *(float4*)&o[4];
  }
}

// ---------------- one LSTM step ----------------
__launch_bounds__(256, 4)
__global__ void k_lstm_step(const float* __restrict__ h_in, float* __restrict__ h_out,
                            float* __restrict__ c_state, const float* __restrict__ xg,
                            const float* __restrict__ w_hh, int tstep)
{
  __shared__ float ws[4*256];
  __shared__ float hs[32*260];
  __shared__ float part[2*128];
  __shared__ float gs[128];
  const int t  = threadIdx.x;
  const int u  = blockIdx.x >> 1;
  const int b0 = (blockIdx.x & 1) * 32;

  {
    int gate = t >> 6, c4 = (t & 63) * 4;
    float4 v = *(const float4*)(w_hh + (long long)(gate*256 + u)*256 + c4);
    *(float4*)&ws[gate*256 + c4] = v;
  }
  #pragma unroll
  for (int i = 0; i < 8; ++i){
    int idx = i*256 + t;
    int b = idx >> 6, c4 = (idx & 63) * 4;
    float4 v = *(const float4*)(h_in + (long long)(b0 + b)*256 + c4);
    *(float4*)&hs[b*260 + c4] = v;
  }
  __syncthreads();

  const int b  = t & 31;
  const int g  = (t >> 5) & 3;
  const int kd = t >> 7;
  float s = 0.f;
  const float* hp = &hs[b*260 + kd*128];
  const float* wp = &ws[g*256 + kd*128];
  #pragma unroll
  for (int k4 = 0; k4 < 32; ++k4){
    float4 h4 = *(const float4*)(hp + k4*4);
    float4 w4 = *(const float4*)(wp + k4*4);
    s += h4.x*w4.x + h4.y*w4.y + h4.z*w4.z + h4.w*w4.w;
  }
  part[kd*128 + b*4 + g] = s;
  __syncthreads();

  if (t < 128){
    int bb = t >> 2, gg = t & 3;
    const float* xp = xg + ((long long)(b0 + bb)*NL + tstep)*1024;
    gs[t] = part[t] + part[128 + t] + xp[gg*256 + u];
  }
  __syncthreads();

  if (t < 32){
    float gi = gs[t*4+0], gf = gs[t*4+1], gG = gs[t*4+2], go = gs[t*4+3];
    int bb = b0 + t;
    float c_old = c_state[bb*256 + u];
    float c_new = sigf(gf)*c_old + sigf(gi)*tanhf(gG);
    c_state[bb*256 + u] = c_new;
    h_out[bb*256 + u] = sigf(go)*tanhf(c_new);
  }
}

// ---------------- global mean pool (hi/lo bf16 input), chunk-parallel ----------------
__launch_bounds__(256, 8)
__global__ void k_pool(const ushort* __restrict__ EH, const ushort* __restrict__ EL,
                       const int* __restrict__ batch,
                       float* __restrict__ gsum, float* __restrict__ gcnt)
{
  __shared__ int bs[64];
  __shared__ int uni;
  __shared__ float spf[8*256];
  const int t  = threadIdx.x;
  const int m0 = blockIdx.x * 64;
  const int r  = t >> 5;        // row-lane 0..7
  const int c  = t & 31;        // colgroup 0..31 (8 elems each)
  if (t == 0) uni = 1;
  if (t < 64){
    int n = m0 + t;
    bs[t] = (n < NN) ? batch[n] : -1;
  }
  __syncthreads();
  if (t < 64 && bs[t] != bs[0]) uni = 0;
  __syncthreads();

  const ushort* eh = EH + (long long)m0*ND + c*8;
  const ushort* el = EL + (long long)m0*ND + c*8;

  if (uni){
    float a[8];
    #pragma unroll
    for (int j = 0; j < 8; ++j) a[j] = 0.f;
    #pragma unroll
    for (int i = 0; i < 8; ++i){
      const int row = r*8 + i;
      const uint4 hv = *(const uint4*)(eh + (long long)row*ND);
      const uint4 lv = *(const uint4*)(el + (long long)row*ND);
      const ushort* hp = (const ushort*)&hv;
      const ushort* lp = (const ushort*)&lv;
      #pragma unroll
      for (int j = 0; j < 8; ++j) a[j] += bf2f(hp[j]) + bf2f(lp[j]);
    }
    #pragma unroll
    for (int j = 0; j < 8; ++j) spf[r*256 + c*8 + j] = a[j];
    __syncthreads();
    float s = spf[t] + spf[256+t] + spf[512+t] + spf[768+t]
            + spf[1024+t] + spf[1280+t] + spf[1536+t] + spf[1792+t];
    const int g = bs[0];
    unsafeAtomicAdd(&gsum[g*256 + t], s);
    if (t == 0) unsafeAtomicAdd(&gcnt[g], 64.0f);
  } else {
    float a[8];
    #pragma unroll
    for (int j = 0; j < 8; ++j) a[j] = 0.f;
    int cur = -1, cnt = 0;
    #pragma unroll
    for (int i = 0; i < 8; ++i){
      const int row = r*8 + i;
      const int g = bs[row];
      if (g != cur){
        if (cur >= 0){
          #pragma unroll
          for (int j = 0; j < 8; ++j) unsafeAtomicAdd(&gsum[cur*256 + c*8 + j], a[j]);
          if (c == 0) unsafeAtomicAdd(&gcnt[cur], (float)cnt);
        }
        #pragma unroll
        for (int j = 0; j < 8; ++j) a[j] = 0.f;
        cnt = 0; cur = g;
      }
      if (g >= 0){
        const uint4 hv = *(const uint4*)(eh + (long long)row*ND);
        const uint4 lv = *(const uint4*)(el + (long long)row*ND);
        const ushort* hp = (const ushort*)&hv;
        const ushort* lp = (const ushort*)&lv;
        #pragma unroll
        for (int j = 0; j < 8; ++j) a[j] += bf2f(hp[j]) + bf2f(lp[j]);
        ++cnt;
      }
    }
    if (cur >= 0){
      #pragma unroll
      for (int j = 0; j < 8; ++j) unsafeAtomicAdd(&gsum[cur*256 + c*8 + j], a[j]);
      if (c == 0) unsafeAtomicAdd(&gcnt[cur], (float)cnt);
    }
  }
}

// ---------------- scorer MLP (pool-finalize + concat fused in) ----------------
__global__ void k_score(const float* __restrict__ gsum, const float* __restrict__ gcnt,
                        const float* __restrict__ hfin, const float* __restrict__ wm1,
                        const float* __restrict__ bm1, const float* __restrict__ wm2,
                        const float* __restrict__ bm2, float* __restrict__ out)
{
  __shared__ float cs[512];
  __shared__ float red[4];
  const int b = blockIdx.x, t = threadIdx.x;
  float inv = 1.0f / fmaxf(gcnt[b], 1.0f);
  cs[t]       = gsum[b*256 + t] * inv;
  cs[256 + t] = hfin[b*256 + t];
  __syncthreads();
  float v = 0.f;
  #pragma unroll 4
  for (int k = 0; k < 512; ++k) v = fmaf(cs[k], wm1[(long long)k*256 + t], v);
  v = fmaxf(v + bm1[t], 0.f) * wm2[t];
  #pragma unroll
  for (int off = 32; off > 0; off >>= 1) v += __shfl_down(v, off, 64);
  if ((t & 63) == 0) red[t >> 6] = v;
  __syncthreads();
  if (t == 0) out[b] = red[0] + red[1] + red[2] + red[3] + bm2[0];
}

} // namespace

extern "C" void kernel_launch(void* const* d_in, const int* in_sizes, int n_in,
                              void* d_out, int out_size, void* d_ws, size_t ws_size,
                              hipStream_t stream)
{
  const float* x     = (const float*)d_in[0];
  const int*   eidx  = (const int*)  d_in[1];
  const int*   batch = (const int*)  d_in[2];
  const int*   paths = (const int*)  d_in[3];
  const float* w1l   = (const float*)d_in[4];
  const float* b1l   = (const float*)d_in[5];
  const float* w1r   = (const float*)d_in[6];
  const float* w2l   = (const float*)d_in[7];
  const float* b2l   = (const float*)d_in[8];
  const float* w2r   = (const float*)d_in[9];
  const float* w_ih  = (const float*)d_in[10];
  const float* w_hh  = (const float*)d_in[11];
  const float* b_ih  = (const float*)d_in[12];
  const float* b_hh  = (const float*)d_in[13];
  const float* wm1   = (const float*)d_in[14];
  const float* bm1   = (const float*)d_in[15];
  const float* wm2   = (const float*)d_in[16];
  const float* bm2   = (const float*)d_in[17];

  const int* src = eidx;        // edge_index[0]
  const int* dst = eidx + NE;   // edge_index[1]

  // workspace layout (same footprint as the original session, ~138 MB)
  float* w    = (float*)d_ws;
  float* bufA = w;                         // region0: gather out hi/lo (2 x NN*ND ushort)
  float* bufB = bufA + (long long)NN*ND;   // region1: h1 hi/lo -> node_emb hi/lo (in-place)
  float* xg   = bufB + (long long)NN*ND;   // 2048*1024 floats
  float* gsum = xg   + 2048*1024;          // 64*256
  float* gcnt = gsum + NB*ND;              // 64
  float* h0   = gcnt + 64;                 // 64*256
  float* c0   = h0   + NB*ND;              // 64*256
  float* h1   = c0   + NB*ND;              // 64*256
  ushort* wt1H = (ushort*)(h1 + NB*ND);    // 256*512 each (bf16, fragment-swizzled)
  ushort* wt1L = wt1H + 256*512;
  ushort* wt2H = wt1L + 256*512;
  ushort* wt2L = wt2H + 256*512;
  ushort* fb16 = wt2L + 256*512;           // N*256 bf16: x RNE copy (gather-1 input)

  ushort* A1H = (ushort*)bufA;             // gather mean, hi
  ushort* A1L = A1H + (long long)NN*ND;    // gather mean, lo
  ushort* h1H = (ushort*)bufB;             // h1 RNE-hi (layer1 out) -> node_emb hi (layer2, in-place)
  ushort* h1L = h1H + (long long)NN*ND;    // h1 residual-lo       -> node_emb lo

  // CSR scratch aliased into xg region (dead until k_xgate runs, after layer 2)
  int* cnt    = (int*)xg;        // 50432
  int* offs   = cnt    + 50432;  // 50432
  int* cursor = offs   + 50432;  // 50432
  int* bsum   = cursor + 50432;  // 256
  int* bsum2  = bsum   + 256;    // 256
  int* csr    = bsum2  + 256;    // 800000

  // ---- weight prep (fragment-swizzled bf16 hi/lo split) ----
  k_wsplit<<<512, 256, 0, stream>>>(w1l, w1r, wt1H, wt1L);
  k_wsplit<<<512, 256, 0, stream>>>(w2l, w2r, wt2H, wt2L);

  // ---- x -> bf16 RNE copy (gather-1 input) ----
  k_tobf16<<<(NN*ND/8 + 255)/256, 256, 0, stream>>>(x, fb16);

  // ---- build CSR (counting sort by dst), shared by both layers ----
  hipMemsetAsync(cnt, 0, 50432*sizeof(int), stream);
  k_hist<<<1024, 256, 0, stream>>>(dst, cnt);
  k_scan_block<<<NSCAN, 256, 0, stream>>>(cnt, offs, bsum);
  k_scan_top<<<1, 256, 0, stream>>>(bsum, bsum2);
  k_scan_add<<<NSCAN, 256, 0, stream>>>(offs, bsum2, cursor);
  k_fill<<<1024, 256, 0, stream>>>(src, dst, cursor, csr);

  // ---- layer 1: gather-mean (pre-split); GEMM A2 = x fp32 (alias-free), relu ----
  k_gather_bf16<<<NN, 256, 0, stream>>>(fb16, offs, csr, A1H, A1L);
  k_gemm<1,1><<<782, 256, 0, stream>>>(A1H, A1L, nullptr, nullptr, x,
                                       wt1H, wt1L, b1l, h1H, h1L);

  // ---- layer 2: gather over RNE(relu(h1)) = h1H; GEMM all-pre-split, in-place ----
  k_gather_bf16<<<NN, 256, 0, stream>>>(h1H, offs, csr, A1H, A1L);
  k_gemm<0,0><<<782, 256, 0, stream>>>(A1H, A1L, h1H, h1L, nullptr,
                                       wt2H, wt2L, b2l, h1H, h1L);

  // ---- global mean pool (chunk-parallel, vectorized) ----
  hipMemsetAsync(gsum, 0, (NB*ND + 64)*sizeof(float), stream);
  k_pool<<<NPOOL, 256, 0, stream>>>(h1H, h1L, batch, gsum, gcnt);

  // ---- LSTM input gates (overwrites the CSR alias region — CSR dead by now) ----
  k_xgate<<<dim3((NB*NL)/64, 1024/256), 256, 0, stream>>>(h1H, h1L, paths, w_ih, b_ih, b_hh, xg);

  // ---- LSTM recurrence: 32 launches, ping-pong h buffers ----
  hipMemsetAsync(h0, 0, 2*(size_t)NB*ND*sizeof(float), stream);  // h0 + c0
  for (int ts = 0; ts < NL; ++ts){
    float* hin  = (ts & 1) ? h1 : h0;
    float* hout = (ts & 1) ? h0 : h1;
    k_lstm_step<<<512, 256, 0, stream>>>(hin, hout, c0, xg, w_hh, ts);
  }
  // ts=31 wrote h0 -> final hidden state

  // ---- fused concat + scorer ----
  k_score<<<NB, 256, 0, stream>>>(gsum, gcnt, h0, wm1, bm1, wm2, bm2, (float*)d_out);
}